// Round 2
// baseline (3299.234 us; speedup 1.0000x reference)
//
#include <hip/hip_runtime.h>
#include <math.h>

// Problem constants
#define B_   4096
#define N_   64
#define D_   12
#define SS_  5
#define I_   7
#define H_   256
#define M1_  512
#define M2_  512
#define A_   81
#define KT_  9            // 8 k-tiles for h (K=256) + 1 for x (K=7 padded to 32)

typedef _Float16 f16;
typedef f16   f16x8 __attribute__((ext_vector_type(8)));
typedef float f32x4 __attribute__((ext_vector_type(4)));

__device__ __forceinline__ void fma4(float4& a, float s, const float4 w) {
  a.x = fmaf(s, w.x, a.x);
  a.y = fmaf(s, w.y, a.y);
  a.z = fmaf(s, w.z, a.z);
  a.w = fmaf(s, w.w, a.w);
}

__device__ __forceinline__ float4 relu4(float4 v) {
  v.x = fmaxf(v.x, 0.f); v.y = fmaxf(v.y, 0.f);
  v.z = fmaxf(v.z, 0.f); v.w = fmaxf(v.w, 0.f);
  return v;
}

// ---------------------------------------------------------------------------
// Kernel 0: pack LSTM weights into MFMA-B layout, fp16 hi/lo split.
// Packed column p = w*128 + g*32 + uu  (wave w, gate g, unit ju = w*32+uu).
// Wpk[kt][p][k32] with k = kt*32+k32 over [h(256) | x(7) pad(25)].
// ---------------------------------------------------------------------------
__global__ void pack_weights(const float* __restrict__ W_ih,
                             const float* __restrict__ W_hh,
                             const float* __restrict__ b_ih,
                             const float* __restrict__ b_hh,
                             f16* __restrict__ Wpk_hi,
                             f16* __restrict__ Wpk_lo,
                             float* __restrict__ bsum_p) {
  const int idx = blockIdx.x * blockDim.x + threadIdx.x;
  if (idx < KT_ * 1024 * 32) {
    const int k32 = idx & 31;
    const int p   = (idx >> 5) & 1023;
    const int kt  = idx >> 15;
    const int w   = p >> 7;
    const int r   = p & 127;
    const int g   = r >> 5;
    const int uu  = r & 31;
    const int row = g * H_ + w * 32 + uu;     // row in original (4H, K) weights
    float v = 0.f;
    if (kt < 8)        v = W_hh[row * H_ + kt * 32 + k32];
    else if (k32 < I_) v = W_ih[row * I_ + k32];
    const f16 hi = (f16)v;
    Wpk_hi[idx] = hi;
    Wpk_lo[idx] = (f16)(v - (float)hi);
  }
  if (idx < 1024) {
    const int w = idx >> 7, r = idx & 127, g = r >> 5, uu = r & 31;
    const int row = g * H_ + w * 32 + uu;
    bsum_p[idx] = b_ih[row] + b_hh[row];
  }
}

// ---------------------------------------------------------------------------
// Kernel 1: distance + stable descending rank-sort + gather.
// xbuf: f16 [t][B][7]; selfbuf: f32 [B][5].
// ---------------------------------------------------------------------------
__global__ void sort_gather(const float* __restrict__ state,
                            f16* __restrict__ xbuf,
                            float* __restrict__ selfbuf) {
  const int b = blockIdx.x;
  const int e = threadIdx.x;                 // 0..63, one wave
  const float* row = state + ((size_t)b * N_ + e) * D_;
  const float4* r4 = (const float4*)row;
  const float4 v0 = r4[0], v1 = r4[1], v2 = r4[2];
  float s[12];
  s[0]=v0.x; s[1]=v0.y; s[2]=v0.z;  s[3]=v0.w;
  s[4]=v1.x; s[5]=v1.y; s[6]=v1.z;  s[7]=v1.w;
  s[8]=v2.x; s[9]=v2.y; s[10]=v2.z; s[11]=v2.w;

  const float s5 = s[5], s6 = s[6];
  const float d = (s5 != 0.f && s6 != 0.f) ? sqrtf(s5 * s5 + s6 * s6) : INFINITY;

  __shared__ float dd[64];
  dd[e] = d;
  __syncthreads();

  int rank = 0;
  #pragma unroll
  for (int j = 0; j < 64; ++j) {
    const float dj = dd[j];
    rank += (dj > d || (dj == d && j < e)) ? 1 : 0;
  }

  f16* xo = xbuf + ((size_t)rank * B_ + b) * I_;
  #pragma unroll
  for (int f = 0; f < I_; ++f) xo[f] = (f16)s[SS_ + f];

  if (e == 0) {
    #pragma unroll
    for (int i = 0; i < SS_; ++i) selfbuf[b * SS_ + i] = s[i];
  }
}

// ---------------------------------------------------------------------------
// Kernel 2: MFMA LSTM. 256 blocks x 512 threads (8 waves); block owns 16
// batches. Per step: G[16x1024] = [h|x][16x288] @ Wpk[288x1024] via
// mfma_f32_16x16x32_f16 with 3-term fp16 hi/lo split (~fp32 accuracy).
// Wave w owns packed cols [128w,128w+128): tiles {2g,2g+1} = gate g of units
// w*32+l15 and w*32+16+l15. Lane ends with all 4 gates of 2 units x 4 batches.
// ---------------------------------------------------------------------------
__global__ __launch_bounds__(512) void lstm_kernel(
    const f16* __restrict__ xbuf,      // [64][B][7]
    const f16* __restrict__ Wpk_hi,    // [9][1024][32]
    const f16* __restrict__ Wpk_lo,
    const float* __restrict__ bsum_p,  // [1024] packed-col bias
    float* __restrict__ hnbuf) {       // [B][256] fp32
  const int tid = threadIdx.x;
  const int l   = tid & 63;
  const int w   = tid >> 6;             // wave 0..7
  const int l15 = l & 15;
  const int lg  = l >> 4;               // 0..3
  const int b0  = blockIdx.x << 4;      // 16 batches per block

  __shared__ f16 hhi_s[16][264];        // h hi, padded row (528B stride -> 2-way)
  __shared__ f16 hlo_s[16][264];        // h lo
  __shared__ f16 x_s[16 * I_];

  for (int i = tid; i < 16 * 264; i += 512) {
    ((f16*)hhi_s)[i] = (f16)0.f;
    ((f16*)hlo_s)[i] = (f16)0.f;
  }

  // bias[g][u] for this lane's two units (packed col = w*128 + g*32 + u*16 + l15)
  float bias[4][2];
  #pragma unroll
  for (int g = 0; g < 4; ++g) {
    bias[g][0] = bsum_p[w * 128 + g * 32 + l15];
    bias[g][1] = bsum_p[w * 128 + g * 32 + 16 + l15];
  }

  // per-lane W offset (f16 units): (p)*32 + lg*8 with p = w*128 + nt*16 + l15
  const int wbase = w * 4096 + l15 * 32 + lg * 8;

  float c_[4][2];
  #pragma unroll
  for (int q = 0; q < 4; ++q) { c_[q][0] = 0.f; c_[q][1] = 0.f; }

  for (int t = 0; t < 64; ++t) {
    if (tid < 16 * I_) x_s[tid] = xbuf[(size_t)t * (B_ * I_) + b0 * I_ + tid];
    __syncthreads();   // x ready; prev-step h hi/lo writes visible

    // x A-fragment (kt=8): rows=batch, k=lg*8+j valid only for k<7 (lanes lg==0)
    f16x8 ax = {(f16)0.f,(f16)0.f,(f16)0.f,(f16)0.f,(f16)0.f,(f16)0.f,(f16)0.f,(f16)0.f};
    if (lg == 0) {
      #pragma unroll
      for (int j = 0; j < I_; ++j) ax[j] = x_s[l15 * I_ + j];
    }

    f32x4 acc[8];
    #pragma unroll
    for (int nt = 0; nt < 8; ++nt) acc[nt] = (f32x4){0.f, 0.f, 0.f, 0.f};

    #pragma unroll
    for (int kt = 0; kt < 8; ++kt) {
      const f16x8 ahi = *(const f16x8*)&hhi_s[l15][kt * 32 + lg * 8];
      const f16x8 alo = *(const f16x8*)&hlo_s[l15][kt * 32 + lg * 8];
      const f16* bph = Wpk_hi + kt * 32768 + wbase;
      const f16* bpl = Wpk_lo + kt * 32768 + wbase;
      #pragma unroll
      for (int nt = 0; nt < 8; ++nt) {
        const f16x8 bhi = *(const f16x8*)(bph + nt * 512);
        const f16x8 blo = *(const f16x8*)(bpl + nt * 512);
        acc[nt] = __builtin_amdgcn_mfma_f32_16x16x32_f16(ahi, bhi, acc[nt], 0, 0, 0);
        acc[nt] = __builtin_amdgcn_mfma_f32_16x16x32_f16(ahi, blo, acc[nt], 0, 0, 0);
        acc[nt] = __builtin_amdgcn_mfma_f32_16x16x32_f16(alo, bhi, acc[nt], 0, 0, 0);
      }
    }
    { // x k-tile (kt=8); A-lo is zero (x already fp16-rounded at gather)
      const f16* bph = Wpk_hi + 8 * 32768 + wbase;
      const f16* bpl = Wpk_lo + 8 * 32768 + wbase;
      #pragma unroll
      for (int nt = 0; nt < 8; ++nt) {
        const f16x8 bhi = *(const f16x8*)(bph + nt * 512);
        const f16x8 blo = *(const f16x8*)(bpl + nt * 512);
        acc[nt] = __builtin_amdgcn_mfma_f32_16x16x32_f16(ax, bhi, acc[nt], 0, 0, 0);
        acc[nt] = __builtin_amdgcn_mfma_f32_16x16x32_f16(ax, blo, acc[nt], 0, 0, 0);
      }
    }
    __syncthreads();   // all h_s reads complete before overwrite

    // epilogue: D row = lg*4+q (batch), tiles {0,1}=i {2,3}=f {4,5}=g {6,7}=o
    #pragma unroll
    for (int q = 0; q < 4; ++q) {
      const int rrow = lg * 4 + q;
      #pragma unroll
      for (int u = 0; u < 2; ++u) {
        const float gi = acc[0 + u][q] + bias[0][u];
        const float gf = acc[2 + u][q] + bias[1][u];
        const float gg = acc[4 + u][q] + bias[2][u];
        const float go = acc[6 + u][q] + bias[3][u];
        const float si = 1.f / (1.f + expf(-gi));
        const float sf = 1.f / (1.f + expf(-gf));
        const float so = 1.f / (1.f + expf(-go));
        const float cn = sf * c_[q][u] + si * tanhf(gg);
        c_[q][u] = cn;
        const float h = so * tanhf(cn);
        const int uidx = w * 32 + u * 16 + l15;
        const f16 hhi = (f16)h;
        hhi_s[rrow][uidx] = hhi;
        hlo_s[rrow][uidx] = (f16)(h - (float)hhi);
        if (t == 63) hnbuf[(size_t)(b0 + rrow) * H_ + uidx] = h;
      }
    }
  }
}

// ---------------------------------------------------------------------------
// Kernel 3: fused MLP head (unchanged). 512 blocks x 256 threads, 8 batches.
// ---------------------------------------------------------------------------
__global__ __launch_bounds__(256) void mlp_kernel(
    const float* __restrict__ selfb, const float* __restrict__ hnbuf,
    const float* __restrict__ W1, const float* __restrict__ b1,
    const float* __restrict__ W2, const float* __restrict__ b2,
    const float* __restrict__ Wv, const float* __restrict__ bv,
    float* __restrict__ out) {
  const int tid = threadIdx.x;
  const int b0  = blockIdx.x << 3;
  const int tb  = tid >> 6;
  const int tn  = tid & 63;

  __shared__ float a0[8][264];
  __shared__ float a1[8][M1_];
  __shared__ float a2[8][M2_];

  for (int i = tid; i < 8 * SS_; i += 256)
    a0[i / SS_][i % SS_] = selfb[b0 * SS_ + i];
  for (int i = tid; i < 8 * H_; i += 256)
    a0[i >> 8][SS_ + (i & 255)] = hnbuf[((size_t)b0 << 8) + i];
  __syncthreads();

  float4 acc[2][2];

  { // layer 1: K=261, N=512
    const float4* W14 = (const float4*)W1;
    const float4* b14 = (const float4*)b1;
    #pragma unroll
    for (int q = 0; q < 2; ++q) { acc[q][0] = b14[tn]; acc[q][1] = b14[tn + 64]; }
    for (int k = 0; k < SS_ + H_; ++k) {
      const float4 w0 = W14[k * 128 + tn];
      const float4 w1 = W14[k * 128 + tn + 64];
      #pragma unroll
      for (int q = 0; q < 2; ++q) {
        const float av = a0[(tb << 1) + q][k];
        fma4(acc[q][0], av, w0);
        fma4(acc[q][1], av, w1);
      }
    }
    #pragma unroll
    for (int q = 0; q < 2; ++q) {
      const int bi = (tb << 1) + q;
      *(float4*)&a1[bi][tn << 2]        = relu4(acc[q][0]);
      *(float4*)&a1[bi][(tn + 64) << 2] = relu4(acc[q][1]);
    }
  }
  __syncthreads();

  { // layer 2: K=512, N=512
    const float4* W24 = (const float4*)W2;
    const float4* b24 = (const float4*)b2;
    #pragma unroll
    for (int q = 0; q < 2; ++q) { acc[q][0] = b24[tn]; acc[q][1] = b24[tn + 64]; }
    for (int k = 0; k < M1_; ++k) {
      const float4 w0 = W24[k * 128 + tn];
      const float4 w1 = W24[k * 128 + tn + 64];
      #pragma unroll
      for (int q = 0; q < 2; ++q) {
        const float av = a1[(tb << 1) + q][k];
        fma4(acc[q][0], av, w0);
        fma4(acc[q][1], av, w1);
      }
    }
    #pragma unroll
    for (int q = 0; q < 2; ++q) {
      const int bi = (tb << 1) + q;
      *(float4*)&a2[bi][tn << 2]        = relu4(acc[q][0]);
      *(float4*)&a2[bi][(tn + 64) << 2] = relu4(acc[q][1]);
    }
  }
  __syncthreads();

  // layer 3: K=512, N=81
  for (int idx = tid; idx < 8 * A_; idx += 256) {
    const int bi = idx / A_;
    const int n  = idx - bi * A_;
    float sum = bv[n];
    for (int k = 0; k < M2_; ++k)
      sum = fmaf(a2[bi][k], Wv[k * A_ + n], sum);
    out[(size_t)(b0 + bi) * A_ + n] = sum;
  }
}

// ---------------------------------------------------------------------------
extern "C" void kernel_launch(void* const* d_in, const int* in_sizes, int n_in,
                              void* d_out, int out_size, void* d_ws, size_t ws_size,
                              hipStream_t stream) {
  const float* state = (const float*)d_in[0];
  const float* W_ih  = (const float*)d_in[1];
  const float* W_hh  = (const float*)d_in[2];
  const float* b_ih  = (const float*)d_in[3];
  const float* b_hh  = (const float*)d_in[4];
  const float* W1    = (const float*)d_in[5];
  const float* b1    = (const float*)d_in[6];
  const float* W2    = (const float*)d_in[7];
  const float* b2    = (const float*)d_in[8];
  const float* Wv    = (const float*)d_in[9];
  const float* bv    = (const float*)d_in[10];
  float* out = (float*)d_out;

  // workspace layout (bytes, all 16B-aligned); total ~9.13 MB
  char* ws = (char*)d_ws;
  f16*   Wpk_hi = (f16*)(ws);                 // 9*1024*32 f16 = 589824 B
  f16*   Wpk_lo = (f16*)(ws + 589824);        // 589824 B
  float* bsum_p = (float*)(ws + 1179648);     // 4096 B
  f16*   xbuf   = (f16*)(ws + 1183744);       // 64*4096*7 f16 = 3670016 B
  float* selfb  = (float*)(ws + 4853760);     // 4096*5 f32 = 81920 B
  float* hnbuf  = (float*)(ws + 4935680);     // 4096*256 f32 = 4194304 B

  pack_weights<<<dim3(1152), dim3(256), 0, stream>>>(W_ih, W_hh, b_ih, b_hh,
                                                     Wpk_hi, Wpk_lo, bsum_p);
  sort_gather<<<dim3(B_), dim3(64), 0, stream>>>(state, xbuf, selfb);
  lstm_kernel<<<dim3(B_ / 16), dim3(512), 0, stream>>>(xbuf, Wpk_hi, Wpk_lo,
                                                       bsum_p, hnbuf);
  mlp_kernel<<<dim3(B_ / 8), dim3(256), 0, stream>>>(selfb, hnbuf, W1, b1, W2, b2,
                                                     Wv, bv, out);
}

// Round 3
// 2664.572 us; speedup vs baseline: 1.2382x; 1.2382x over previous
//
#include <hip/hip_runtime.h>
#include <math.h>

// Problem constants
#define B_   4096
#define N_   64
#define SS_  5
#define I_   7
#define H_   256
#define M1_  512
#define M2_  512
#define A_   81
#define KT_  9            // 8 k-tiles for h (K=256) + 1 for x (K=7 padded to 32)

typedef _Float16 f16;
typedef f16   f16x8 __attribute__((ext_vector_type(8)));
typedef float f32x4 __attribute__((ext_vector_type(4)));

__device__ __forceinline__ void fma4(float4& a, float s, const float4 w) {
  a.x = fmaf(s, w.x, a.x);
  a.y = fmaf(s, w.y, a.y);
  a.z = fmaf(s, w.z, a.z);
  a.w = fmaf(s, w.w, a.w);
}

__device__ __forceinline__ float4 relu4(float4 v) {
  v.x = fmaxf(v.x, 0.f); v.y = fmaxf(v.y, 0.f);
  v.z = fmaxf(v.z, 0.f); v.w = fmaxf(v.w, 0.f);
  return v;
}

// ---------------------------------------------------------------------------
// Kernel 0: pack LSTM weights into MFMA-B layout, fp16 hi/lo split.
// 16-wave column split: packed col p = w*64 + g*16 + uu  (wave w∈[0,16),
// gate g, unit u = w*16+uu). Wpk[kt][p][k32], k = kt*32+k32 over
// [h(256) | x(7) pad(25)].
// ---------------------------------------------------------------------------
__global__ void pack_weights(const float* __restrict__ W_ih,
                             const float* __restrict__ W_hh,
                             const float* __restrict__ b_ih,
                             const float* __restrict__ b_hh,
                             f16* __restrict__ Wpk_hi,
                             f16* __restrict__ Wpk_lo,
                             float* __restrict__ bsum_p) {
  const int idx = blockIdx.x * blockDim.x + threadIdx.x;
  if (idx < KT_ * 1024 * 32) {
    const int k32 = idx & 31;
    const int p   = (idx >> 5) & 1023;
    const int kt  = idx >> 15;
    const int w   = p >> 6;
    const int r   = p & 63;
    const int g   = r >> 4;
    const int uu  = r & 15;
    const int row = g * H_ + w * 16 + uu;     // row in original (4H, K) weights
    float v = 0.f;
    if (kt < 8)        v = W_hh[row * H_ + kt * 32 + k32];
    else if (k32 < I_) v = W_ih[row * I_ + k32];
    const f16 hi = (f16)v;
    Wpk_hi[idx] = hi;
    Wpk_lo[idx] = (f16)(v - (float)hi);
  }
  if (idx < 1024) {
    const int w = idx >> 6, r = idx & 63, g = r >> 4, uu = r & 15;
    const int row = g * H_ + w * 16 + uu;
    bsum_p[idx] = b_ih[row] + b_hh[row];
  }
}

// ---------------------------------------------------------------------------
// Kernel 1: distance + stable descending rank-sort + gather.
// xbuf: f16 [t][B][7]; selfbuf: f32 [B][5].
// ---------------------------------------------------------------------------
__global__ void sort_gather(const float* __restrict__ state,
                            f16* __restrict__ xbuf,
                            float* __restrict__ selfbuf) {
  const int b = blockIdx.x;
  const int e = threadIdx.x;                 // 0..63, one wave
  const float* row = state + ((size_t)b * N_ + e) * 12;
  const float4* r4 = (const float4*)row;
  const float4 v0 = r4[0], v1 = r4[1], v2 = r4[2];
  float s[12];
  s[0]=v0.x; s[1]=v0.y; s[2]=v0.z;  s[3]=v0.w;
  s[4]=v1.x; s[5]=v1.y; s[6]=v1.z;  s[7]=v1.w;
  s[8]=v2.x; s[9]=v2.y; s[10]=v2.z; s[11]=v2.w;

  const float s5 = s[5], s6 = s[6];
  const float d = (s5 != 0.f && s6 != 0.f) ? sqrtf(s5 * s5 + s6 * s6) : INFINITY;

  __shared__ float dd[64];
  dd[e] = d;
  __syncthreads();

  int rank = 0;
  #pragma unroll
  for (int j = 0; j < 64; ++j) {
    const float dj = dd[j];
    rank += (dj > d || (dj == d && j < e)) ? 1 : 0;
  }

  f16* xo = xbuf + ((size_t)rank * B_ + b) * I_;
  #pragma unroll
  for (int f = 0; f < I_; ++f) xo[f] = (f16)s[SS_ + f];

  if (e == 0) {
    #pragma unroll
    for (int i = 0; i < SS_; ++i) selfbuf[b * SS_ + i] = s[i];
  }
}

// ---------------------------------------------------------------------------
// Kernel 2: persistent-weight MFMA LSTM. 256 blocks x 1024 threads (16
// waves), block owns 16 batches; wave w owns packed cols [64w, 64w+64)
// (gates g of units w*16+l15) and keeps its hi/lo B-fragments in VGPRs for
// all 64 steps (~288 VGPRs). h round-trips LDS pre-arranged in A-fragment
// order: ahf/alf [kt][batch][40] f16, 80B row stride (f16x8-aligned, banks
// spread). 3-term fp16 hi/lo split per step (~fp32 accuracy).
// ---------------------------------------------------------------------------
__global__ __launch_bounds__(1024) void lstm_kernel(
    const f16* __restrict__ xbuf,      // [64][B][7]
    const f16* __restrict__ Wpk_hi,    // [9][1024][32]
    const f16* __restrict__ Wpk_lo,
    const float* __restrict__ bsum_p,  // [1024] packed-col bias
    float* __restrict__ hnbuf) {       // [B][256] fp32
  const int tid = threadIdx.x;
  const int l   = tid & 63;
  const int w   = tid >> 6;             // wave 0..15
  const int l15 = l & 15;
  const int lg  = l >> 4;               // 0..3
  const int b0  = blockIdx.x << 4;      // 16 batches per block

  __shared__ f16 ahf[8 * 16 * 40];      // h-hi A-frags: [kt][b][lg*8+j], 80B rows
  __shared__ f16 alf[8 * 16 * 40];      // h-lo
  __shared__ f16 x_s[16 * I_];

  for (int i = tid; i < 8 * 16 * 40; i += 1024) {
    ahf[i] = (f16)0.f;
    alf[i] = (f16)0.f;
  }

  // --- persistent B fragments (one-time L2 broadcast) ---
  f16x8 Bh[KT_][4], Bl[KT_][4];
  {
    const int base = w * 2048 + l15 * 32 + lg * 8;
    #pragma unroll
    for (int kt = 0; kt < KT_; ++kt) {
      #pragma unroll
      for (int g = 0; g < 4; ++g) {
        const int off = kt * 32768 + g * 512 + base;
        Bh[kt][g] = *(const f16x8*)(Wpk_hi + off);
        Bl[kt][g] = *(const f16x8*)(Wpk_lo + off);
      }
    }
  }

  float bias[4];
  #pragma unroll
  for (int g = 0; g < 4; ++g) bias[g] = bsum_p[w * 64 + g * 16 + l15];

  const int ra = l15 * 40 + lg * 8;               // reader offset in kt-slab
  const int u  = w * 16 + l15;                    // this lane's hidden unit
  const int wb = (u >> 5) * 640 + ((u >> 3) & 3) * 8 + (u & 7);  // writer base

  float c_[4] = {0.f, 0.f, 0.f, 0.f};

  #pragma unroll 1
  for (int t = 0; t < 64; ++t) {
    if (tid < 16 * I_) x_s[tid] = xbuf[(size_t)t * (B_ * I_) + b0 * I_ + tid];
    __syncthreads();   // x ready; prev-step h frag writes visible

    // x A-fragment (kt=8): row=batch=l15, k=lg*8+j valid for k<7 (lg==0)
    f16x8 ax = {(f16)0.f,(f16)0.f,(f16)0.f,(f16)0.f,
                (f16)0.f,(f16)0.f,(f16)0.f,(f16)0.f};
    if (lg == 0) {
      #pragma unroll
      for (int j = 0; j < I_; ++j) ax[j] = x_s[l15 * I_ + j];
    }

    f32x4 acc[4];
    #pragma unroll
    for (int g = 0; g < 4; ++g) acc[g] = (f32x4){0.f, 0.f, 0.f, 0.f};

    #pragma unroll
    for (int kt = 0; kt < 8; ++kt) {
      const f16x8 ahi = *(const f16x8*)&ahf[kt * 640 + ra];
      const f16x8 alo = *(const f16x8*)&alf[kt * 640 + ra];
      #pragma unroll
      for (int g = 0; g < 4; ++g) {
        acc[g] = __builtin_amdgcn_mfma_f32_16x16x32_f16(ahi, Bh[kt][g], acc[g], 0, 0, 0);
        acc[g] = __builtin_amdgcn_mfma_f32_16x16x32_f16(ahi, Bl[kt][g], acc[g], 0, 0, 0);
        acc[g] = __builtin_amdgcn_mfma_f32_16x16x32_f16(alo, Bh[kt][g], acc[g], 0, 0, 0);
      }
    }
    #pragma unroll
    for (int g = 0; g < 4; ++g) {
      acc[g] = __builtin_amdgcn_mfma_f32_16x16x32_f16(ax, Bh[8][g], acc[g], 0, 0, 0);
      acc[g] = __builtin_amdgcn_mfma_f32_16x16x32_f16(ax, Bl[8][g], acc[g], 0, 0, 0);
    }
    __syncthreads();   // all frag reads complete before overwrite

    // epilogue: lane owns unit u for batches lg*4+q
    #pragma unroll
    for (int q = 0; q < 4; ++q) {
      const int b = lg * 4 + q;
      const float gi = acc[0][q] + bias[0];
      const float gf = acc[1][q] + bias[1];
      const float gg = acc[2][q] + bias[2];
      const float go = acc[3][q] + bias[3];
      const float si = 1.f / (1.f + expf(-gi));
      const float sf = 1.f / (1.f + expf(-gf));
      const float so = 1.f / (1.f + expf(-go));
      const float cn = sf * c_[q] + si * tanhf(gg);
      c_[q] = cn;
      const float h = so * tanhf(cn);
      const f16 hh = (f16)h;
      ahf[wb + b * 40] = hh;
      alf[wb + b * 40] = (f16)(h - (float)hh);
      if (t == 63) hnbuf[(size_t)(b0 + b) * H_ + u] = h;
    }
  }
}

// ---------------------------------------------------------------------------
// Kernel 3: fused MLP head. 512 blocks x 256 threads, 8 batches per block.
// ---------------------------------------------------------------------------
__global__ __launch_bounds__(256) void mlp_kernel(
    const float* __restrict__ selfb, const float* __restrict__ hnbuf,
    const float* __restrict__ W1, const float* __restrict__ b1,
    const float* __restrict__ W2, const float* __restrict__ b2,
    const float* __restrict__ Wv, const float* __restrict__ bv,
    float* __restrict__ out) {
  const int tid = threadIdx.x;
  const int b0  = blockIdx.x << 3;
  const int tb  = tid >> 6;
  const int tn  = tid & 63;

  __shared__ float a0[8][264];
  __shared__ float a1[8][M1_];
  __shared__ float a2[8][M2_];

  for (int i = tid; i < 8 * SS_; i += 256)
    a0[i / SS_][i % SS_] = selfb[b0 * SS_ + i];
  for (int i = tid; i < 8 * H_; i += 256)
    a0[i >> 8][SS_ + (i & 255)] = hnbuf[((size_t)b0 << 8) + i];
  __syncthreads();

  float4 acc[2][2];

  { // layer 1: K=261, N=512
    const float4* W14 = (const float4*)W1;
    const float4* b14 = (const float4*)b1;
    #pragma unroll
    for (int q = 0; q < 2; ++q) { acc[q][0] = b14[tn]; acc[q][1] = b14[tn + 64]; }
    for (int k = 0; k < SS_ + H_; ++k) {
      const float4 w0 = W14[k * 128 + tn];
      const float4 w1 = W14[k * 128 + tn + 64];
      #pragma unroll
      for (int q = 0; q < 2; ++q) {
        const float av = a0[(tb << 1) + q][k];
        fma4(acc[q][0], av, w0);
        fma4(acc[q][1], av, w1);
      }
    }
    #pragma unroll
    for (int q = 0; q < 2; ++q) {
      const int bi = (tb << 1) + q;
      *(float4*)&a1[bi][tn << 2]        = relu4(acc[q][0]);
      *(float4*)&a1[bi][(tn + 64) << 2] = relu4(acc[q][1]);
    }
  }
  __syncthreads();

  { // layer 2: K=512, N=512
    const float4* W24 = (const float4*)W2;
    const float4* b24 = (const float4*)b2;
    #pragma unroll
    for (int q = 0; q < 2; ++q) { acc[q][0] = b24[tn]; acc[q][1] = b24[tn + 64]; }
    for (int k = 0; k < M1_; ++k) {
      const float4 w0 = W24[k * 128 + tn];
      const float4 w1 = W24[k * 128 + tn + 64];
      #pragma unroll
      for (int q = 0; q < 2; ++q) {
        const float av = a1[(tb << 1) + q][k];
        fma4(acc[q][0], av, w0);
        fma4(acc[q][1], av, w1);
      }
    }
    #pragma unroll
    for (int q = 0; q < 2; ++q) {
      const int bi = (tb << 1) + q;
      *(float4*)&a2[bi][tn << 2]        = relu4(acc[q][0]);
      *(float4*)&a2[bi][(tn + 64) << 2] = relu4(acc[q][1]);
    }
  }
  __syncthreads();

  // layer 3: K=512, N=81
  for (int idx = tid; idx < 8 * A_; idx += 256) {
    const int bi = idx / A_;
    const int n  = idx - bi * A_;
    float sum = bv[n];
    for (int k = 0; k < M2_; ++k)
      sum = fmaf(a2[bi][k], Wv[k * A_ + n], sum);
    out[(size_t)(b0 + bi) * A_ + n] = sum;
  }
}

// ---------------------------------------------------------------------------
extern "C" void kernel_launch(void* const* d_in, const int* in_sizes, int n_in,
                              void* d_out, int out_size, void* d_ws, size_t ws_size,
                              hipStream_t stream) {
  const float* state = (const float*)d_in[0];
  const float* W_ih  = (const float*)d_in[1];
  const float* W_hh  = (const float*)d_in[2];
  const float* b_ih  = (const float*)d_in[3];
  const float* b_hh  = (const float*)d_in[4];
  const float* W1    = (const float*)d_in[5];
  const float* b1    = (const float*)d_in[6];
  const float* W2    = (const float*)d_in[7];
  const float* b2    = (const float*)d_in[8];
  const float* Wv    = (const float*)d_in[9];
  const float* bv    = (const float*)d_in[10];
  float* out = (float*)d_out;

  // workspace layout (bytes, all 16B-aligned); total ~9.13 MB
  char* ws = (char*)d_ws;
  f16*   Wpk_hi = (f16*)(ws);                 // 9*1024*32 f16 = 589824 B
  f16*   Wpk_lo = (f16*)(ws + 589824);        // 589824 B
  float* bsum_p = (float*)(ws + 1179648);     // 4096 B
  f16*   xbuf   = (f16*)(ws + 1183744);       // 64*4096*7 f16 = 3670016 B
  float* selfb  = (float*)(ws + 4853760);     // 4096*5 f32 = 81920 B
  float* hnbuf  = (float*)(ws + 4935680);     // 4096*256 f32 = 4194304 B

  pack_weights<<<dim3(1152), dim3(256), 0, stream>>>(W_ih, W_hh, b_ih, b_hh,
                                                     Wpk_hi, Wpk_lo, bsum_p);
  sort_gather<<<dim3(B_), dim3(64), 0, stream>>>(state, xbuf, selfb);
  lstm_kernel<<<dim3(B_ / 16), dim3(1024), 0, stream>>>(xbuf, Wpk_hi, Wpk_lo,
                                                        bsum_p, hnbuf);
  mlp_kernel<<<dim3(B_ / 8), dim3(256), 0, stream>>>(selfb, hnbuf, W1, b1, W2, b2,
                                                     Wv, bv, out);
}

// Round 4
// 555.160 us; speedup vs baseline: 5.9428x; 4.7996x over previous
//
#include <hip/hip_runtime.h>
#include <math.h>

// Problem constants
#define B_   4096
#define N_   64
#define SS_  5
#define I_   7
#define H_   256
#define M1_  512
#define M2_  512
#define A_   81

typedef _Float16 f16;
typedef f16   f16x8 __attribute__((ext_vector_type(8)));
typedef float f32x4 __attribute__((ext_vector_type(4)));

__device__ __forceinline__ void fma4(float4& a, float s, const float4 w) {
  a.x = fmaf(s, w.x, a.x);
  a.y = fmaf(s, w.y, a.y);
  a.z = fmaf(s, w.z, a.z);
  a.w = fmaf(s, w.w, a.w);
}

__device__ __forceinline__ float4 relu4(float4 v) {
  v.x = fmaxf(v.x, 0.f); v.y = fmaxf(v.y, 0.f);
  v.z = fmaxf(v.z, 0.f); v.w = fmaxf(v.w, 0.f);
  return v;
}

// ---------------------------------------------------------------------------
// Kernel 0: pack LSTM weights, single f16.
// Packed col p = w*128 + g*32 + uu  (wave w in [0,8), gate g, unit u=w*32+uu).
// Wpk[kt][p][k32] (h part, kt<8, k=kt*32+k32). Wxk[p][8] compact x part
// (j<7 real, j=7 zero). bsum_p[p] = b_ih+b_hh.
// ---------------------------------------------------------------------------
__global__ void pack_weights(const float* __restrict__ W_ih,
                             const float* __restrict__ W_hh,
                             const float* __restrict__ b_ih,
                             const float* __restrict__ b_hh,
                             f16* __restrict__ Wpk,
                             f16* __restrict__ Wxk,
                             float* __restrict__ bsum_p) {
  const int idx = blockIdx.x * blockDim.x + threadIdx.x;
  if (idx < 8 * 1024 * 32) {               // 262144
    const int k32 = idx & 31;
    const int p   = (idx >> 5) & 1023;
    const int kt  = idx >> 15;
    const int w   = p >> 7;
    const int r   = p & 127;
    const int g   = r >> 5;
    const int uu  = r & 31;
    const int row = g * H_ + w * 32 + uu;  // row in original (4H, K) weights
    Wpk[idx] = (f16)W_hh[row * H_ + kt * 32 + k32];
  }
  if (idx < 1024 * 8) {
    const int j = idx & 7;
    const int p = idx >> 3;
    const int w = p >> 7, r = p & 127, g = r >> 5, uu = r & 31;
    const int row = g * H_ + w * 32 + uu;
    Wxk[idx] = (j < I_) ? (f16)W_ih[row * I_ + j] : (f16)0.f;
  }
  if (idx < 1024) {
    const int w = idx >> 7, r = idx & 127, g = r >> 5, uu = r & 31;
    const int row = g * H_ + w * 32 + uu;
    bsum_p[idx] = b_ih[row] + b_hh[row];
  }
}

// ---------------------------------------------------------------------------
// Kernel 1: distance + stable descending rank-sort + gather.
// xbuf: f16 [t][B][7]; selfbuf: f32 [B][5].
// ---------------------------------------------------------------------------
__global__ void sort_gather(const float* __restrict__ state,
                            f16* __restrict__ xbuf,
                            float* __restrict__ selfbuf) {
  const int b = blockIdx.x;
  const int e = threadIdx.x;                 // 0..63, one wave
  const float* row = state + ((size_t)b * N_ + e) * 12;
  const float4* r4 = (const float4*)row;
  const float4 v0 = r4[0], v1 = r4[1], v2 = r4[2];
  float s[12];
  s[0]=v0.x; s[1]=v0.y; s[2]=v0.z;  s[3]=v0.w;
  s[4]=v1.x; s[5]=v1.y; s[6]=v1.z;  s[7]=v1.w;
  s[8]=v2.x; s[9]=v2.y; s[10]=v2.z; s[11]=v2.w;

  const float s5 = s[5], s6 = s[6];
  const float d = (s5 != 0.f && s6 != 0.f) ? sqrtf(s5 * s5 + s6 * s6) : INFINITY;

  __shared__ float dd[64];
  dd[e] = d;
  __syncthreads();

  int rank = 0;
  #pragma unroll
  for (int j = 0; j < 64; ++j) {
    const float dj = dd[j];
    rank += (dj > d || (dj == d && j < e)) ? 1 : 0;
  }

  f16* xo = xbuf + ((size_t)rank * B_ + b) * I_;
  #pragma unroll
  for (int f = 0; f < I_; ++f) xo[f] = (f16)s[SS_ + f];

  if (e == 0) {
    #pragma unroll
    for (int i = 0; i < SS_; ++i) selfbuf[b * SS_ + i] = s[i];
  }
}

// ---------------------------------------------------------------------------
// Kernel 2: MFMA LSTM, CU-resident weights. 256 blocks x 512 threads (8
// waves = 2/SIMD, 1 block/CU), 16 batches/block. Wave w owns packed cols
// [128w,128w+128): kt 0..5 of W_hh in VGPRs (192), kt 6,7 + x-tile + bias
// in LDS. Single-f16 weights & h (one MFMA term/tile).
// LDS budget: 131072 + 16384 + 8448 + 4096 + 224 = 160224 B.
// ---------------------------------------------------------------------------
__global__ __launch_bounds__(512, 2) void lstm_kernel(
    const f16* __restrict__ xbuf,      // [64][B][7]
    const f16* __restrict__ Wpk,       // [8][1024][32]
    const f16* __restrict__ Wxk,       // [1024][8]
    const float* __restrict__ bsum_p,  // [1024]
    float* __restrict__ hnbuf) {       // [B][256] fp32
  const int tid = threadIdx.x;
  const int l   = tid & 63;
  const int w   = tid >> 6;             // wave 0..7
  const int l15 = l & 15;
  const int lg  = l >> 4;               // 0..3
  const int b0  = blockIdx.x << 4;      // 16 batches per block

  extern __shared__ char smem[];
  f16*   Bl_s = (f16*)smem;                  // [2][1024][32] kt 6,7  131072 B
  f16*   Bx_s = (f16*)(smem + 131072);       // [1024][8]             16384 B
  f16*   h_s  = (f16*)(smem + 147456);       // [16][264]              8448 B
  float* bs_s = (float*)(smem + 155904);     // [1024]                 4096 B
  f16*   x_s  = (f16*)(smem + 160000);       // [16*7]                  224 B

  // --- one-time staging (coalesced linear copies) ---
  {
    const f16x8* src = (const f16x8*)(Wpk + 6 * 32768);
    f16x8* dst = (f16x8*)Bl_s;
    for (int i = tid; i < 8192; i += 512) dst[i] = src[i];
    const f16x8* sx = (const f16x8*)Wxk;
    f16x8* dx = (f16x8*)Bx_s;
    for (int i = tid; i < 1024; i += 512) dx[i] = sx[i];
    for (int i = tid; i < 1024; i += 512) bs_s[i] = bsum_p[i];
    for (int i = tid; i < 16 * 264; i += 512) h_s[i] = (f16)0.f;
  }

  // --- persistent B fragments, kt 0..5 (192 VGPRs) ---
  const int base = w * 4096 + l15 * 32 + lg * 8;   // f16 units
  f16x8 B[6][8];
  #pragma unroll
  for (int kt = 0; kt < 6; ++kt) {
    #pragma unroll
    for (int ct = 0; ct < 8; ++ct)
      B[kt][ct] = *(const f16x8*)(Wpk + kt * 32768 + ct * 512 + base);
  }

  float c_[2][4];
  #pragma unroll
  for (int uh = 0; uh < 2; ++uh)
    #pragma unroll
    for (int q = 0; q < 4; ++q) c_[uh][q] = 0.f;

  const int hrd = l15 * 264 + lg * 8;   // h A-frag read base (f16 idx)

  __syncthreads();   // staging visible

  #pragma unroll 1
  for (int t = 0; t < 64; ++t) {
    if (tid < 16 * I_) x_s[tid] = xbuf[(size_t)t * (B_ * I_) + b0 * I_ + tid];
    __syncthreads();   // x ready; prev-step h writes visible

    // x A-fragment: row=batch=l15, k=lg*8+j valid only for lg==0, j<7
    f16x8 ax = {(f16)0.f,(f16)0.f,(f16)0.f,(f16)0.f,
                (f16)0.f,(f16)0.f,(f16)0.f,(f16)0.f};
    if (lg == 0) {
      #pragma unroll
      for (int j = 0; j < I_; ++j) ax[j] = x_s[l15 * I_ + j];
    }

    f32x4 acc[8];
    #pragma unroll
    for (int ct = 0; ct < 8; ++ct) acc[ct] = (f32x4){0.f, 0.f, 0.f, 0.f};

    // kt 0..5: B from registers
    #pragma unroll
    for (int kt = 0; kt < 6; ++kt) {
      const f16x8 Af = *(const f16x8*)&h_s[hrd + kt * 32];
      #pragma unroll
      for (int ct = 0; ct < 8; ++ct)
        acc[ct] = __builtin_amdgcn_mfma_f32_16x16x32_f16(Af, B[kt][ct], acc[ct], 0, 0, 0);
    }
    // kt 6,7: B from LDS
    #pragma unroll
    for (int k2 = 0; k2 < 2; ++k2) {
      const f16x8 Af = *(const f16x8*)&h_s[hrd + (6 + k2) * 32];
      #pragma unroll
      for (int ct = 0; ct < 8; ++ct) {
        const f16x8 Bv = *(const f16x8*)(Bl_s + k2 * 32768 + ct * 512 + base);
        acc[ct] = __builtin_amdgcn_mfma_f32_16x16x32_f16(Af, Bv, acc[ct], 0, 0, 0);
      }
    }
    // x tile: B from LDS (lg>0 lanes multiply A=0 -> value irrelevant)
    #pragma unroll
    for (int ct = 0; ct < 8; ++ct) {
      const f16x8 Bv = *(const f16x8*)(Bx_s + (w * 128 + ct * 16 + l15) * 8);
      acc[ct] = __builtin_amdgcn_mfma_f32_16x16x32_f16(ax, Bv, acc[ct], 0, 0, 0);
    }
    __syncthreads();   // all h_s / x_s reads complete before overwrite

    // epilogue: lane owns units u = w*32 + uh*16 + l15 for batches lg*4+q
    #pragma unroll
    for (int uh = 0; uh < 2; ++uh) {
      const float bi_ = bs_s[w * 128 + 0 * 32 + uh * 16 + l15];
      const float bf_ = bs_s[w * 128 + 1 * 32 + uh * 16 + l15];
      const float bg_ = bs_s[w * 128 + 2 * 32 + uh * 16 + l15];
      const float bo_ = bs_s[w * 128 + 3 * 32 + uh * 16 + l15];
      const int u = w * 32 + uh * 16 + l15;
      #pragma unroll
      for (int q = 0; q < 4; ++q) {
        const int b = lg * 4 + q;
        const float gi = acc[0 + uh][q] + bi_;
        const float gf = acc[2 + uh][q] + bf_;
        const float gg = acc[4 + uh][q] + bg_;
        const float go = acc[6 + uh][q] + bo_;
        const float si = 1.f / (1.f + __expf(-gi));
        const float sf = 1.f / (1.f + __expf(-gf));
        const float so = 1.f / (1.f + __expf(-go));
        const float tg = 1.f - 2.f / (__expf(2.f * gg) + 1.f);
        const float cn = sf * c_[uh][q] + si * tg;
        c_[uh][q] = cn;
        const float tc = 1.f - 2.f / (__expf(2.f * cn) + 1.f);
        const float h = so * tc;
        h_s[b * 264 + u] = (f16)h;
        if (t == 63) hnbuf[(size_t)(b0 + b) * H_ + u] = h;
      }
    }
  }
}

// ---------------------------------------------------------------------------
// Kernel 3: fused MLP head. 512 blocks x 256 threads, 8 batches per block.
// ---------------------------------------------------------------------------
__global__ __launch_bounds__(256) void mlp_kernel(
    const float* __restrict__ selfb, const float* __restrict__ hnbuf,
    const float* __restrict__ W1, const float* __restrict__ b1,
    const float* __restrict__ W2, const float* __restrict__ b2,
    const float* __restrict__ Wv, const float* __restrict__ bv,
    float* __restrict__ out) {
  const int tid = threadIdx.x;
  const int b0  = blockIdx.x << 3;
  const int tb  = tid >> 6;
  const int tn  = tid & 63;

  __shared__ float a0[8][264];
  __shared__ float a1[8][M1_];
  __shared__ float a2[8][M2_];

  for (int i = tid; i < 8 * SS_; i += 256)
    a0[i / SS_][i % SS_] = selfb[b0 * SS_ + i];
  for (int i = tid; i < 8 * H_; i += 256)
    a0[i >> 8][SS_ + (i & 255)] = hnbuf[((size_t)b0 << 8) + i];
  __syncthreads();

  float4 acc[2][2];

  { // layer 1: K=261, N=512
    const float4* W14 = (const float4*)W1;
    const float4* b14 = (const float4*)b1;
    #pragma unroll
    for (int q = 0; q < 2; ++q) { acc[q][0] = b14[tn]; acc[q][1] = b14[tn + 64]; }
    for (int k = 0; k < SS_ + H_; ++k) {
      const float4 w0 = W14[k * 128 + tn];
      const float4 w1 = W14[k * 128 + tn + 64];
      #pragma unroll
      for (int q = 0; q < 2; ++q) {
        const float av = a0[(tb << 1) + q][k];
        fma4(acc[q][0], av, w0);
        fma4(acc[q][1], av, w1);
      }
    }
    #pragma unroll
    for (int q = 0; q < 2; ++q) {
      const int bi = (tb << 1) + q;
      *(float4*)&a1[bi][tn << 2]        = relu4(acc[q][0]);
      *(float4*)&a1[bi][(tn + 64) << 2] = relu4(acc[q][1]);
    }
  }
  __syncthreads();

  { // layer 2: K=512, N=512
    const float4* W24 = (const float4*)W2;
    const float4* b24 = (const float4*)b2;
    #pragma unroll
    for (int q = 0; q < 2; ++q) { acc[q][0] = b24[tn]; acc[q][1] = b24[tn + 64]; }
    for (int k = 0; k < M1_; ++k) {
      const float4 w0 = W24[k * 128 + tn];
      const float4 w1 = W24[k * 128 + tn + 64];
      #pragma unroll
      for (int q = 0; q < 2; ++q) {
        const float av = a1[(tb << 1) + q][k];
        fma4(acc[q][0], av, w0);
        fma4(acc[q][1], av, w1);
      }
    }
    #pragma unroll
    for (int q = 0; q < 2; ++q) {
      const int bi = (tb << 1) + q;
      *(float4*)&a2[bi][tn << 2]        = relu4(acc[q][0]);
      *(float4*)&a2[bi][(tn + 64) << 2] = relu4(acc[q][1]);
    }
  }
  __syncthreads();

  // layer 3: K=512, N=81
  for (int idx = tid; idx < 8 * A_; idx += 256) {
    const int bi = idx / A_;
    const int n  = idx - bi * A_;
    float sum = bv[n];
    for (int k = 0; k < M2_; ++k)
      sum = fmaf(a2[bi][k], Wv[k * A_ + n], sum);
    out[(size_t)(b0 + bi) * A_ + n] = sum;
  }
}

// ---------------------------------------------------------------------------
extern "C" void kernel_launch(void* const* d_in, const int* in_sizes, int n_in,
                              void* d_out, int out_size, void* d_ws, size_t ws_size,
                              hipStream_t stream) {
  const float* state = (const float*)d_in[0];
  const float* W_ih  = (const float*)d_in[1];
  const float* W_hh  = (const float*)d_in[2];
  const float* b_ih  = (const float*)d_in[3];
  const float* b_hh  = (const float*)d_in[4];
  const float* W1    = (const float*)d_in[5];
  const float* b1    = (const float*)d_in[6];
  const float* W2    = (const float*)d_in[7];
  const float* b2    = (const float*)d_in[8];
  const float* Wv    = (const float*)d_in[9];
  const float* bv    = (const float*)d_in[10];
  float* out = (float*)d_out;

  // workspace layout (bytes, 16B-aligned); total ~8.5 MB
  char* ws = (char*)d_ws;
  f16*   Wpk    = (f16*)(ws);                 // 8*1024*32 f16 = 524288 B
  f16*   Wxk    = (f16*)(ws + 524288);        // 1024*8 f16    = 16384 B
  float* bsum_p = (float*)(ws + 540672);      // 1024 f32      = 4096 B
  f16*   xbuf   = (f16*)(ws + 544768);        // 64*4096*7 f16 = 3670016 B
  float* selfb  = (float*)(ws + 4214784);     // 4096*5 f32    = 81920 B
  float* hnbuf  = (float*)(ws + 4296704);     // 4096*256 f32  = 4194304 B

  pack_weights<<<dim3(1024), dim3(256), 0, stream>>>(W_ih, W_hh, b_ih, b_hh,
                                                     Wpk, Wxk, bsum_p);
  sort_gather<<<dim3(B_), dim3(64), 0, stream>>>(state, xbuf, selfb);
  lstm_kernel<<<dim3(B_ / 16), dim3(512), 160224, stream>>>(xbuf, Wpk, Wxk,
                                                            bsum_p, hnbuf);
  mlp_kernel<<<dim3(B_ / 8), dim3(256), 0, stream>>>(selfb, hnbuf, W1, b1, W2, b2,
                                                     Wv, bv, out);
}

// Round 5
// 450.221 us; speedup vs baseline: 7.3280x; 1.2331x over previous
//
#include <hip/hip_runtime.h>
#include <math.h>

// Problem constants
#define B_   4096
#define N_   64
#define SS_  5
#define I_   7
#define H_   256
#define M1_  512
#define M2_  512
#define A_   81

typedef _Float16 f16;
typedef f16   f16x8 __attribute__((ext_vector_type(8)));
typedef float f32x4 __attribute__((ext_vector_type(4)));

__device__ __forceinline__ void fma4(float4& a, float s, const float4 w) {
  a.x = fmaf(s, w.x, a.x);
  a.y = fmaf(s, w.y, a.y);
  a.z = fmaf(s, w.z, a.z);
  a.w = fmaf(s, w.w, a.w);
}

__device__ __forceinline__ float4 relu4(float4 v) {
  v.x = fmaxf(v.x, 0.f); v.y = fmaxf(v.y, 0.f);
  v.z = fmaxf(v.z, 0.f); v.w = fmaxf(v.w, 0.f);
  return v;
}

__device__ __forceinline__ float sigm_(float x) {
  return __builtin_amdgcn_rcpf(1.f + __expf(-x));
}
__device__ __forceinline__ float tanh_(float x) {
  return 1.f - 2.f * __builtin_amdgcn_rcpf(__expf(2.f * x) + 1.f);
}

// ---------------------------------------------------------------------------
// Kernel 0: pack LSTM weights, single f16.
// Gate-col view: p = w*128 + g*32 + uu  (wave w in [0,8), gate g, unit
// u = w*32+uu); MFMA-tile view: p = w*128 + ct*16 + l15 (ct = g*2 + uu/16).
// Wpk[kt][p][k32]      kt 0..5 (register frags; global coalesced loads)
// Wpk_lds[k2][w][ct][l15][lg][j]  kt 6,7 lane-major (conflict-free LDS reads)
// Wxk[p][8]            x part (j<7 real, j=7 zero), broadcast reads
// bsum_p[p] = b_ih+b_hh.
// ---------------------------------------------------------------------------
__global__ void pack_weights(const float* __restrict__ W_ih,
                             const float* __restrict__ W_hh,
                             const float* __restrict__ b_ih,
                             const float* __restrict__ b_hh,
                             f16* __restrict__ Wpk,
                             f16* __restrict__ Wpk_lds,
                             f16* __restrict__ Wxk,
                             float* __restrict__ bsum_p) {
  const int idx = blockIdx.x * blockDim.x + threadIdx.x;
  if (idx < 6 * 1024 * 32) {               // register k-tiles 0..5
    const int k32 = idx & 31;
    const int p   = (idx >> 5) & 1023;
    const int kt  = idx >> 15;
    const int w   = p >> 7;
    const int r   = p & 127;
    const int g   = r >> 5;
    const int uu  = r & 31;
    const int row = g * H_ + w * 32 + uu;
    Wpk[idx] = (f16)W_hh[row * H_ + kt * 32 + k32];
  }
  if (idx < 65536) {                        // LDS k-tiles 6,7, lane-major
    const int j   = idx & 7;
    const int lg  = (idx >> 3) & 3;
    const int l15 = (idx >> 5) & 15;
    const int ct  = (idx >> 9) & 7;
    const int w   = (idx >> 12) & 7;
    const int k2  = idx >> 15;
    const int g   = ct >> 1;
    const int uu  = (ct & 1) * 16 + l15;
    const int row = g * H_ + w * 32 + uu;
    const int k   = (6 + k2) * 32 + lg * 8 + j;
    Wpk_lds[idx] = (f16)W_hh[row * H_ + k];
  }
  if (idx < 1024 * 8) {
    const int j = idx & 7;
    const int p = idx >> 3;
    const int w = p >> 7, r = p & 127, g = r >> 5, uu = r & 31;
    const int row = g * H_ + w * 32 + uu;
    Wxk[idx] = (j < I_) ? (f16)W_ih[row * I_ + j] : (f16)0.f;
  }
  if (idx < 1024) {
    const int w = idx >> 7, r = idx & 127, g = r >> 5, uu = r & 31;
    const int row = g * H_ + w * 32 + uu;
    bsum_p[idx] = b_ih[row] + b_hh[row];
  }
}

// ---------------------------------------------------------------------------
// Kernel 1: distance + stable descending rank-sort + gather.
// xbuf: f16 [t][B][7]; selfbuf: f32 [B][5].
// ---------------------------------------------------------------------------
__global__ void sort_gather(const float* __restrict__ state,
                            f16* __restrict__ xbuf,
                            float* __restrict__ selfbuf) {
  const int b = blockIdx.x;
  const int e = threadIdx.x;                 // 0..63, one wave
  const float* row = state + ((size_t)b * N_ + e) * 12;
  const float4* r4 = (const float4*)row;
  const float4 v0 = r4[0], v1 = r4[1], v2 = r4[2];
  float s[12];
  s[0]=v0.x; s[1]=v0.y; s[2]=v0.z;  s[3]=v0.w;
  s[4]=v1.x; s[5]=v1.y; s[6]=v1.z;  s[7]=v1.w;
  s[8]=v2.x; s[9]=v2.y; s[10]=v2.z; s[11]=v2.w;

  const float s5 = s[5], s6 = s[6];
  const float d = (s5 != 0.f && s6 != 0.f) ? sqrtf(s5 * s5 + s6 * s6) : INFINITY;

  __shared__ float dd[64];
  dd[e] = d;
  __syncthreads();

  int rank = 0;
  #pragma unroll
  for (int j = 0; j < 64; ++j) {
    const float dj = dd[j];
    rank += (dj > d || (dj == d && j < e)) ? 1 : 0;
  }

  f16* xo = xbuf + ((size_t)rank * B_ + b) * I_;
  #pragma unroll
  for (int f = 0; f < I_; ++f) xo[f] = (f16)s[SS_ + f];

  if (e == 0) {
    #pragma unroll
    for (int i = 0; i < SS_; ++i) selfbuf[b * SS_ + i] = s[i];
  }
}

// ---------------------------------------------------------------------------
// Kernel 2: MFMA LSTM, CU-resident weights. 256 blocks x 512 threads (8
// waves = 2/SIMD, 1 block/CU), 16 batches/block. Wave w owns packed cols
// [128w,128w+128): kt 0..5 of W_hh in VGPRs (192, residency FORCED by asm),
// kt 6,7 + x-tile in LDS (lane-major, conflict-free). h in LDS as A-frag
// slabs [kt][lg][b][8] (conflict-free b128 reads). Fast sigmoid/tanh via
// v_exp + v_rcp. LDS: 131072 + 16384 + 8192 + 224 = 155872 B.
// ---------------------------------------------------------------------------
__global__ __launch_bounds__(512, 2) void lstm_kernel(
    const f16* __restrict__ xbuf,      // [64][B][7]
    const f16* __restrict__ Wpk,       // [6][1024][32]
    const f16* __restrict__ Wpk_lds,   // [2][8][8][16][4][8]
    const f16* __restrict__ Wxk,       // [1024][8]
    const float* __restrict__ bsum_p,  // [1024]
    float* __restrict__ hnbuf) {       // [B][256] fp32
  const int tid = threadIdx.x;
  const int l   = tid & 63;
  const int w   = tid >> 6;             // wave 0..7
  const int l15 = l & 15;
  const int lg  = l >> 4;               // 0..3
  const int b0  = blockIdx.x << 4;      // 16 batches per block

  extern __shared__ char smem[];
  f16* Bl_s = (f16*)smem;                  // [2][8][8][16][4][8]  131072 B
  f16* Bx_s = (f16*)(smem + 131072);       // [1024][8]             16384 B
  f16* h_s  = (f16*)(smem + 147456);       // [8][4][16][8]          8192 B
  f16* x_s  = (f16*)(smem + 155648);       // [16*7]                  224 B

  // --- one-time staging (coalesced linear copies) ---
  {
    const f16x8* src = (const f16x8*)Wpk_lds;
    f16x8* dst = (f16x8*)Bl_s;
    for (int i = tid; i < 8192; i += 512) dst[i] = src[i];
    const f16x8* sx = (const f16x8*)Wxk;
    f16x8* dx = (f16x8*)Bx_s;
    for (int i = tid; i < 1024; i += 512) dx[i] = sx[i];
    f16x8* hz = (f16x8*)h_s;
    for (int i = tid; i < 512; i += 512)
      hz[i] = (f16x8){(f16)0.f,(f16)0.f,(f16)0.f,(f16)0.f,
                      (f16)0.f,(f16)0.f,(f16)0.f,(f16)0.f};
  }

  // bias in registers
  float bias[4][2];
  #pragma unroll
  for (int g = 0; g < 4; ++g)
    #pragma unroll
    for (int uh = 0; uh < 2; ++uh)
      bias[g][uh] = bsum_p[w * 128 + g * 32 + uh * 16 + l15];

  // --- persistent B fragments, kt 0..5 (192 VGPRs) ---
  const int gbase = w * 4096 + l15 * 32 + lg * 8;   // f16 units
  f16x8 B[6][8];
  #pragma unroll
  for (int kt = 0; kt < 6; ++kt) {
    #pragma unroll
    for (int ct = 0; ct < 8; ++ct)
      B[kt][ct] = *(const f16x8*)(Wpk + kt * 32768 + ct * 512 + gbase);
  }

  const int lbase = (l15 * 4 + lg) * 8;   // lane offset within LDS B subtile
  const int hrd   = lg * 128 + l15 * 8;   // h A-frag read base (+kt*512)
  const int hwb   = w * 512 + ((((l15 >> 3) + 2 * 0) + 0) * 0);  // placeholder

  float c_[2][4];
  #pragma unroll
  for (int uh = 0; uh < 2; ++uh)
    #pragma unroll
    for (int q = 0; q < 4; ++q) c_[uh][q] = 0.f;

  __syncthreads();   // staging visible

  #pragma unroll 1
  for (int t = 0; t < 64; ++t) {
    if (tid < 16 * I_) x_s[tid] = xbuf[(size_t)t * (B_ * I_) + b0 * I_ + tid];
    __syncthreads();   // x ready; prev-step h writes visible

    // force weight-fragment residency (zero-instruction asm barrier per value)
    #pragma unroll
    for (int kt = 0; kt < 6; ++kt)
      #pragma unroll
      for (int ct = 0; ct < 8; ++ct)
        asm volatile("" : "+v"(B[kt][ct]));

    // x A-fragment: row=batch=l15, k=lg*8+j valid only for lg==0, j<7
    f16x8 ax = {(f16)0.f,(f16)0.f,(f16)0.f,(f16)0.f,
                (f16)0.f,(f16)0.f,(f16)0.f,(f16)0.f};
    if (lg == 0) {
      #pragma unroll
      for (int j = 0; j < I_; ++j) ax[j] = x_s[l15 * I_ + j];
    }

    f32x4 acc[8];
    #pragma unroll
    for (int ct = 0; ct < 8; ++ct) acc[ct] = (f32x4){0.f, 0.f, 0.f, 0.f};

    // kt 0..5: B from registers
    #pragma unroll
    for (int kt = 0; kt < 6; ++kt) {
      const f16x8 Af = *(const f16x8*)&h_s[kt * 512 + hrd];
      #pragma unroll
      for (int ct = 0; ct < 8; ++ct)
        acc[ct] = __builtin_amdgcn_mfma_f32_16x16x32_f16(Af, B[kt][ct], acc[ct], 0, 0, 0);
    }
    // kt 6,7: B from LDS (lane-major subtiles, conflict-free)
    #pragma unroll
    for (int k2 = 0; k2 < 2; ++k2) {
      const f16x8 Af = *(const f16x8*)&h_s[(6 + k2) * 512 + hrd];
      #pragma unroll
      for (int ct = 0; ct < 8; ++ct) {
        const f16x8 Bv = *(const f16x8*)(Bl_s + k2 * 32768 + (w * 8 + ct) * 512 + lbase);
        acc[ct] = __builtin_amdgcn_mfma_f32_16x16x32_f16(Af, Bv, acc[ct], 0, 0, 0);
      }
    }
    // x tile: B from LDS (all-lg same addr -> broadcast)
    #pragma unroll
    for (int ct = 0; ct < 8; ++ct) {
      const f16x8 Bv = *(const f16x8*)(Bx_s + (w * 128 + ct * 16 + l15) * 8);
      acc[ct] = __builtin_amdgcn_mfma_f32_16x16x32_f16(ax, Bv, acc[ct], 0, 0, 0);
    }
    __syncthreads();   // all h_s / x_s reads complete before overwrite

    // epilogue: lane owns units u = w*32 + uh*16 + l15 for batches lg*4+q
    #pragma unroll
    for (int uh = 0; uh < 2; ++uh) {
      const int u  = w * 32 + uh * 16 + l15;
      const int wb = w * 512 + (uh * 2 + (l15 >> 3)) * 128 + (l15 & 7);
      #pragma unroll
      for (int q = 0; q < 4; ++q) {
        const int b = lg * 4 + q;
        const float gi = acc[0 + uh][q] + bias[0][uh];
        const float gf = acc[2 + uh][q] + bias[1][uh];
        const float gg = acc[4 + uh][q] + bias[2][uh];
        const float go = acc[6 + uh][q] + bias[3][uh];
        const float cn = sigm_(gf) * c_[uh][q] + sigm_(gi) * tanh_(gg);
        c_[uh][q] = cn;
        const float h = sigm_(go) * tanh_(cn);
        h_s[wb + b * 8] = (f16)h;
        if (t == 63) hnbuf[(size_t)(b0 + b) * H_ + u] = h;
      }
    }
  }
  (void)hwb;
}

// ---------------------------------------------------------------------------
// Kernel 3: fused MLP head. 256 blocks x 512 threads, 16 batches per block.
// Dynamic LDS: a0 16x264 + a1 16x512 + a2 16x512 = 82432 B.
// ---------------------------------------------------------------------------
__global__ __launch_bounds__(512) void mlp_kernel(
    const float* __restrict__ selfb, const float* __restrict__ hnbuf,
    const float* __restrict__ W1, const float* __restrict__ b1,
    const float* __restrict__ W2, const float* __restrict__ b2,
    const float* __restrict__ Wv, const float* __restrict__ bv,
    float* __restrict__ out) {
  const int tid = threadIdx.x;
  const int b0  = blockIdx.x << 4;      // 16 batches per block
  const int tb  = tid >> 7;             // 0..3 (batch group)
  const int tn  = tid & 127;            // float4 column group (N=512 -> 128)

  extern __shared__ char smem[];
  float* a0 = (float*)smem;                    // [16][264]
  float* a1 = (float*)(smem + 16896);          // [16][512]
  float* a2 = (float*)(smem + 16896 + 32768);  // [16][512]

  for (int i = tid; i < 16 * SS_; i += 512)
    a0[(i / SS_) * 264 + (i % SS_)] = selfb[b0 * SS_ + i];
  for (int i = tid; i < 16 * H_; i += 512)
    a0[(i >> 8) * 264 + SS_ + (i & 255)] = hnbuf[((size_t)b0 << 8) + i];
  __syncthreads();

  float4 acc[4];

  { // layer 1: K=261, N=512
    const float4* W14 = (const float4*)W1;
    const float4 bb = ((const float4*)b1)[tn];
    #pragma unroll
    for (int q = 0; q < 4; ++q) acc[q] = bb;
    for (int k = 0; k < SS_ + H_; ++k) {
      const float4 w0 = W14[k * 128 + tn];
      #pragma unroll
      for (int q = 0; q < 4; ++q)
        fma4(acc[q], a0[(tb * 4 + q) * 264 + k], w0);
    }
    #pragma unroll
    for (int q = 0; q < 4; ++q)
      *(float4*)&a1[(tb * 4 + q) * 512 + tn * 4] = relu4(acc[q]);
  }
  __syncthreads();

  { // layer 2: K=512, N=512
    const float4* W24 = (const float4*)W2;
    const float4 bb = ((const float4*)b2)[tn];
    #pragma unroll
    for (int q = 0; q < 4; ++q) acc[q] = bb;
    for (int k = 0; k < M1_; ++k) {
      const float4 w0 = W24[k * 128 + tn];
      #pragma unroll
      for (int q = 0; q < 4; ++q)
        fma4(acc[q], a1[(tb * 4 + q) * 512 + k], w0);
    }
    #pragma unroll
    for (int q = 0; q < 4; ++q)
      *(float4*)&a2[(tb * 4 + q) * 512 + tn * 4] = relu4(acc[q]);
  }
  __syncthreads();

  // layer 3: K=512, N=81
  for (int idx = tid; idx < 16 * A_; idx += 512) {
    const int bi = idx / A_;
    const int n  = idx - bi * A_;
    float sum = bv[n];
    for (int k = 0; k < M2_; ++k)
      sum = fmaf(a2[bi * 512 + k], Wv[k * A_ + n], sum);
    out[(size_t)(b0 + bi) * A_ + n] = sum;
  }
}

// ---------------------------------------------------------------------------
extern "C" void kernel_launch(void* const* d_in, const int* in_sizes, int n_in,
                              void* d_out, int out_size, void* d_ws, size_t ws_size,
                              hipStream_t stream) {
  const float* state = (const float*)d_in[0];
  const float* W_ih  = (const float*)d_in[1];
  const float* W_hh  = (const float*)d_in[2];
  const float* b_ih  = (const float*)d_in[3];
  const float* b_hh  = (const float*)d_in[4];
  const float* W1    = (const float*)d_in[5];
  const float* b1    = (const float*)d_in[6];
  const float* W2    = (const float*)d_in[7];
  const float* b2    = (const float*)d_in[8];
  const float* Wv    = (const float*)d_in[9];
  const float* bv    = (const float*)d_in[10];
  float* out = (float*)d_out;

  // workspace layout (bytes, 16B-aligned); total ~8.6 MB
  char* ws = (char*)d_ws;
  f16*   Wpk     = (f16*)(ws);                 // 6*1024*32 f16 = 393216 B
  f16*   Wpk_lds = (f16*)(ws + 393216);        // 65536 f16     = 131072 B
  f16*   Wxk     = (f16*)(ws + 524288);        // 1024*8 f16    = 16384 B
  float* bsum_p  = (float*)(ws + 540672);      // 1024 f32      = 4096 B
  f16*   xbuf    = (f16*)(ws + 544768);        // 64*4096*7 f16 = 3670016 B
  float* selfb   = (float*)(ws + 4214784);     // 4096*5 f32    = 81920 B
  float* hnbuf   = (float*)(ws + 4296704);     // 4096*256 f32  = 4194304 B

  pack_weights<<<dim3(768), dim3(256), 0, stream>>>(W_ih, W_hh, b_ih, b_hh,
                                                    Wpk, Wpk_lds, Wxk, bsum_p);
  sort_gather<<<dim3(B_), dim3(64), 0, stream>>>(state, xbuf, selfb);
  lstm_kernel<<<dim3(B_ / 16), dim3(512), 155872, stream>>>(xbuf, Wpk, Wpk_lds,
                                                            Wxk, bsum_p, hnbuf);
  mlp_kernel<<<dim3(B_ / 16), dim3(512), 82432, stream>>>(selfb, hnbuf, W1, b1,
                                                          W2, b2, Wv, bv, out);
}